// Round 15
// baseline (182.844 us; speedup 1.0000x reference)
//
#include <hip/hip_runtime.h>
#include <hip/hip_bf16.h>
#include <math.h>

#define S_LEN 2048
#define DIM   1024
#define NH    16
#define NKVH  4
#define HD    64
#define KVDIM 256

typedef __hip_bfloat16 bf16;
typedef __attribute__((ext_vector_type(8))) short short8;   // 8 bf16 (4 VGPRs)
typedef __attribute__((ext_vector_type(4))) float f32x4;

__device__ __forceinline__ short bfbits(float v) {
    bf16 t = __float2bfloat16(v);
    return *(short*)&t;
}

// ---------------------------------------------------------------------------
// cast7: grid.y 0-5 = fp32->bf16 casts of the six inputs; grid.y 6 = trig LUT
// (cosT/sinT = radius*cos/sin(pos*angle), exact double formula as verified).
// ---------------------------------------------------------------------------
__global__ __launch_bounds__(256) void cast7(
    const float* __restrict__ x,  const float* __restrict__ Wq,
    const float* __restrict__ Wk, const float* __restrict__ Wv,
    const float* __restrict__ Wg, const float* __restrict__ Wo,
    bf16* __restrict__ xb,  bf16* __restrict__ Wqb,
    bf16* __restrict__ Wkb, bf16* __restrict__ Wvb,
    bf16* __restrict__ Wgb, bf16* __restrict__ Wob,
    float* __restrict__ cosT, float* __restrict__ sinT) {
    if (blockIdx.y == 6) {
        for (int idx = blockIdx.x * 256 + threadIdx.x; idx < S_LEN * 32;
             idx += gridDim.x * 256) {
            const int s = idx >> 5, i = idx & 31;
            float af  = (float)(((double)(2 * i) / 64.0) * 3.14159265358979323846);
            float ang = (float)s * af;
            float radius = 1.0f / (1.0f + 0.01f * (float)s);
            cosT[idx] = radius * (float)cos((double)ang);
            sinT[idx] = radius * (float)sin((double)ang);
        }
        return;
    }
    const float* s; bf16* d; int n;
    switch (blockIdx.y) {
        case 0: s = x;  d = xb;  n = S_LEN * DIM; break;
        case 1: s = Wq; d = Wqb; n = DIM * DIM;   break;
        case 2: s = Wk; d = Wkb; n = KVDIM * DIM; break;
        case 3: s = Wv; d = Wvb; n = KVDIM * DIM; break;
        case 4: s = Wg; d = Wgb; n = KVDIM * DIM; break;
        default: s = Wo; d = Wob; n = DIM * DIM;  break;
    }
    for (int i = (blockIdx.x * 256 + threadIdx.x) * 4; i < n; i += gridDim.x * 1024) {
        float4 v = *(const float4*)(s + i);
        d[i]     = __float2bfloat16(v.x);
        d[i + 1] = __float2bfloat16(v.y);
        d[i + 2] = __float2bfloat16(v.z);
        d[i + 3] = __float2bfloat16(v.w);
    }
}

// ---------------------------------------------------------------------------
// 128x128 MFMA GEMM core, BK=64, 4 waves in 2x2 grid (each 64x64 = 4x4 frags).
// Same verified fragment/epilogue layouts as the R11 64-tile core.
// ---------------------------------------------------------------------------
__device__ __forceinline__ void gemm128_core(
    const bf16* __restrict__ A, const bf16* __restrict__ B,
    float* __restrict__ C, int bm, int bn, int N, int K) {
    __shared__ short As[128 * 72];
    __shared__ short Bs[128 * 72];
    const int tid  = threadIdx.x;
    const int w    = tid >> 6;
    const int lane = tid & 63;
    const int quad = lane >> 4;
    const int lm   = lane & 15;
    const int rw   = w >> 1;           // wave row-half
    const int cw   = w & 1;            // wave col-half
    const int srow = tid >> 1;         // staging row 0..127
    const int skc  = (tid & 1) * 32;   // staging k-offset (shorts)
    const bf16* ap = A + (size_t)(bm + srow) * K + skc;
    const bf16* bp = B + (size_t)(bn + srow) * K + skc;
    f32x4 acc[4][4] = {};
    for (int k0 = 0; k0 < K; k0 += 64) {
        uint4 a0 = *(const uint4*)(ap + k0);
        uint4 a1 = *(const uint4*)(ap + k0 + 8);
        uint4 a2 = *(const uint4*)(ap + k0 + 16);
        uint4 a3 = *(const uint4*)(ap + k0 + 24);
        uint4 b0 = *(const uint4*)(bp + k0);
        uint4 b1 = *(const uint4*)(bp + k0 + 8);
        uint4 b2 = *(const uint4*)(bp + k0 + 16);
        uint4 b3 = *(const uint4*)(bp + k0 + 24);
        *(uint4*)&As[srow * 72 + skc]      = a0;
        *(uint4*)&As[srow * 72 + skc + 8]  = a1;
        *(uint4*)&As[srow * 72 + skc + 16] = a2;
        *(uint4*)&As[srow * 72 + skc + 24] = a3;
        *(uint4*)&Bs[srow * 72 + skc]      = b0;
        *(uint4*)&Bs[srow * 72 + skc + 8]  = b1;
        *(uint4*)&Bs[srow * 72 + skc + 16] = b2;
        *(uint4*)&Bs[srow * 72 + skc + 24] = b3;
        __syncthreads();
        #pragma unroll
        for (int ks = 0; ks < 2; ++ks) {
            short8 af[4], bfr[4];
            #pragma unroll
            for (int i = 0; i < 4; ++i)
                af[i] = *(const short8*)&As[(rw * 64 + i * 16 + lm) * 72 + ks * 32 + quad * 8];
            #pragma unroll
            for (int j = 0; j < 4; ++j)
                bfr[j] = *(const short8*)&Bs[(cw * 64 + j * 16 + lm) * 72 + ks * 32 + quad * 8];
            #pragma unroll
            for (int i = 0; i < 4; ++i)
                #pragma unroll
                for (int j = 0; j < 4; ++j)
                    acc[i][j] = __builtin_amdgcn_mfma_f32_16x16x32_bf16(
                        af[i], bfr[j], acc[i][j], 0, 0, 0);
        }
        __syncthreads();
    }
    #pragma unroll
    for (int i = 0; i < 4; ++i) {
        const int r0 = bm + rw * 64 + i * 16 + quad * 4;
        #pragma unroll
        for (int j = 0; j < 4; ++j) {
            const int col = bn + cw * 64 + j * 16 + lm;
            #pragma unroll
            for (int r = 0; r < 4; ++r)
                C[(size_t)(r0 + r) * N + col] = acc[i][j][r];
        }
    }
}

// Fused Q+K+V+G projection: grid (14, 16). bx<8 -> Q tile; else KVG tiles.
__global__ __launch_bounds__(256, 2) void gemm_qkvg(
    const bf16* __restrict__ xb, const bf16* __restrict__ Wqb,
    const bf16* __restrict__ Wkb, const bf16* __restrict__ Wvb,
    const bf16* __restrict__ Wgb, float* __restrict__ Qp,
    float* __restrict__ KVG) {
    const int c0 = blockIdx.x * 128;
    const bf16* B; float* C; int bn, N;
    if (c0 < DIM) { B = Wqb; C = Qp; bn = c0; N = DIM; }
    else {
        const int t = c0 - DIM;
        const int wsel = t >> 8;
        B = (wsel == 0) ? Wkb : (wsel == 1) ? Wvb : Wgb;
        C = KVG + (size_t)wsel * S_LEN * KVDIM;
        bn = t & 255; N = KVDIM;
    }
    gemm128_core(xb, B, C, blockIdx.y * 128, bn, N, DIM);
}

__global__ __launch_bounds__(256, 2) void gemm_out(
    const bf16* __restrict__ Yb, const bf16* __restrict__ Wob,
    float* __restrict__ C) {
    gemm128_core(Yb, Wob, C, blockIdx.y * 128, blockIdx.x * 128, DIM, DIM);
}

// ---------------------------------------------------------------------------
// Postproc Q+K: grid (S, 20), 64 thr. RMSNorm + rotary via LUT. Q writes
// row-major; K repacks via LDS into 8x16B coalesced chunks of Kpk.
// Kpk: ((((kvh*2+half)*64+kb)*2+g)*64 + (d32>>3)*16 + (s&15))*8 + (d32&7)
// ---------------------------------------------------------------------------
__device__ __forceinline__ float rms_rot_lut(
    const float* __restrict__ p, const float* __restrict__ cosT,
    const float* __restrict__ sinT, int s, int lane, float gain) {
    float x = p[lane];
    float ss = x * x;
    #pragma unroll
    for (int o = 32; o > 0; o >>= 1) ss += __shfl_xor(ss, o);
    float n = x * rsqrtf(ss * (1.0f/64.0f) + 1.1920928955078125e-7f);
    float other = __shfl_xor(n, 32);
    int i = lane & 31;
    float c  = cosT[s * 32 + i];
    float sn = sinT[s * 32 + i];
    return (n * c + ((lane < 32) ? other * sn : -other * sn)) * gain;
}

__global__ __launch_bounds__(64) void postproc_qk(
    const float* __restrict__ Qp, const float* __restrict__ Kp,
    bf16* __restrict__ Qb, bf16* __restrict__ Kpk,
    const float* __restrict__ qgain,
    const float* __restrict__ cosT, const float* __restrict__ sinT) {
    __shared__ short krow[64];
    const int s = blockIdx.x;
    const int unit = blockIdx.y;
    const int lane = threadIdx.x;
    if (unit < NH) {
        float v = rms_rot_lut(Qp + (size_t)s * DIM + unit * HD, cosT, sinT,
                              s, lane, qgain[unit]);
        Qb[(size_t)s * DIM + unit * HD + lane] = __float2bfloat16(v);
    } else {
        const int kvh = unit - NH;
        float v = rms_rot_lut(Kp + (size_t)s * KVDIM + kvh * HD, cosT, sinT,
                              s, lane, 1.0f);
        krow[lane] = bfbits(v);
        asm volatile("s_waitcnt lgkmcnt(0)" ::: "memory");
        if (lane < 8) {
            const int half = lane >> 2, qd = lane & 3;
            short8 chunk = *(const short8*)&krow[half * 32 + qd * 8];
            const int kb = s >> 5, g = (s & 31) >> 4, m = s & 15;
            const size_t ki = ((((size_t)(kvh * 2 + half) * 64 + kb) * 2 + g) * 64
                               + qd * 16 + m) * 8;
            *(short8*)(Kpk + ki) = chunk;
        }
    }
}

// ---------------------------------------------------------------------------
// Postproc V: grid (S/8, NKVH), 64 thr. Lane d handles dim d for 8 keys;
// its 8 j-values form exactly one contiguous 16B Vpk chunk.
// Vpk: ((((kvh*2+half)*64+kb)*2+(d32>>4))*64 + ((s&31)>>3)*16 + (d32&15))*8 + (s&7)
// ---------------------------------------------------------------------------
__global__ __launch_bounds__(64) void postproc_v(
    const float* __restrict__ Vp, const float* __restrict__ Gp,
    bf16* __restrict__ Vpk) {
    const int s0  = blockIdx.x * 8;
    const int kvh = blockIdx.y;
    const int d   = threadIdx.x;
    short8 pv;
    #pragma unroll
    for (int j = 0; j < 8; ++j) {
        const size_t off = (size_t)(s0 + j) * KVDIM + kvh * HD + d;
        float gv = Gp[off];
        pv[j] = bfbits(Vp[off] / (1.0f + __expf(-gv)));
    }
    const int half = d >> 5, d32 = d & 31;
    const int g = d32 >> 4, m = d32 & 15;
    const int kb = s0 >> 5, qd = (s0 & 31) >> 3;
    const size_t vi = ((((size_t)(kvh * 2 + half) * 64 + kb) * 2 + g) * 64
                       + qd * 16 + m) * 8;
    *(short8*)(Vpk + vi) = pv;
}

// ---------------------------------------------------------------------------
// MFMA flash attention (verified R14, unchanged): 1 wave/block, 4096 blocks,
// packed 1KB fragment loads, no-max softmax, O in MFMA C-regs.
// ---------------------------------------------------------------------------
__global__ __launch_bounds__(64, 4) void attn_mfma(
    const bf16* __restrict__ Qb, const bf16* __restrict__ Kpk,
    const bf16* __restrict__ Vpk, float* __restrict__ Ao) {
    __shared__ short PW[640];             // 16 rows x 40 shorts
    const int id    = blockIdx.x;
    const int qtile = 127 - (id >> 5);
    const int hh    = id & 31;
    const int h     = hh >> 1;
    const int half  = hh & 1;
    const int kvh   = h >> 2;
    const int lane  = threadIdx.x;
    const int quad  = lane >> 4;
    const int m     = lane & 15;
    bf16* PWb = (bf16*)PW;

    const int qrow = qtile * 16 + m;
    short8 qf = *(const short8*)(Qb + (size_t)qrow * DIM + h * HD + half * 32 + quad * 8);

    const bf16* kbase = Kpk + (size_t)(kvh * 2 + half) * 64 * 1024 + lane * 8;
    const bf16* vbase = Vpk + (size_t)(kvh * 2 + half) * 64 * 1024 + lane * 8;

    f32x4 o0 = {}, o1 = {};
    float lpart[4] = {0.f, 0.f, 0.f, 0.f};
    const float scale = 0.17677669529663687f;   // 1/sqrt(32)
    const int rbase = qtile * 16 + quad * 4;
    const int nkt = (qtile >> 1) + 1;

    for (int kb = 0; kb < nkt; ++kb) {
        short8 kf0 = *(const short8*)(kbase + kb * 1024);
        short8 kf1 = *(const short8*)(kbase + kb * 1024 + 512);
        f32x4 s0 = {}, s1 = {};
        s0 = __builtin_amdgcn_mfma_f32_16x16x32_bf16(qf, kf0, s0, 0, 0, 0);
        s1 = __builtin_amdgcn_mfma_f32_16x16x32_bf16(qf, kf1, s1, 0, 0, 0);
        short8 vtf0 = *(const short8*)(vbase + kb * 1024);
        short8 vtf1 = *(const short8*)(vbase + kb * 1024 + 512);
        const int kg = kb * 32 + m;
        #pragma unroll
        for (int r = 0; r < 4; ++r) {
            const int rg = rbase + r;
            const float p0 = (kg > rg)      ? 0.f : __expf(s0[r] * scale);
            const float p1 = (kg + 16 > rg) ? 0.f : __expf(s1[r] * scale);
            lpart[r] += p0 + p1;
            PWb[(quad * 4 + r) * 40 + m]      = __float2bfloat16(p0);
            PWb[(quad * 4 + r) * 40 + 16 + m] = __float2bfloat16(p1);
        }
        asm volatile("s_waitcnt lgkmcnt(0)" ::: "memory");
        short8 pf = *(const short8*)&PW[m * 40 + quad * 8];
        o0 = __builtin_amdgcn_mfma_f32_16x16x32_bf16(pf, vtf0, o0, 0, 0, 0);
        o1 = __builtin_amdgcn_mfma_f32_16x16x32_bf16(pf, vtf1, o1, 0, 0, 0);
    }

    #pragma unroll
    for (int r = 0; r < 4; ++r) {
        float v = lpart[r];
        v += __shfl_xor(v, 1);
        v += __shfl_xor(v, 2);
        v += __shfl_xor(v, 4);
        v += __shfl_xor(v, 8);
        lpart[r] = 1.f / v;
    }
    #pragma unroll
    for (int r = 0; r < 4; ++r) {
        float* op = Ao + (size_t)(rbase + r) * DIM + h * HD + half * 32;
        op[m]      = o0[r] * lpart[r];
        op[16 + m] = o1[r] * lpart[r];
    }
}

// ---------------------------------------------------------------------------
// Combine -> bf16 Y (verified)
// ---------------------------------------------------------------------------
__global__ __launch_bounds__(256) void combine_kernel(
    const float* __restrict__ A, const float* __restrict__ lambda_p,
    bf16* __restrict__ Y) {
    const int idx = blockIdx.x * 256 + threadIdx.x;
    const int c = idx & (DIM - 1);
    const int s = idx >> 10;
    const int hh = c >> 6;
    const int d = c & 63;
    const float* base = A + (size_t)s * DIM + hh * HD;
    const float lam = lambda_p[hh];
    float y;
    if (d < 32) y = base[d]      - lam * base[d + 32];
    else        y = base[d - 32] + lam * base[d];
    Y[idx] = __float2bfloat16(y);
}

// ---------------------------------------------------------------------------
// Workspace (32 MB):
//  0-8    Qp fp32 -> Yb bf16 overlays (Qp dead after postproc)
//  8-14   KVG fp32 (Kp 8-10, Vp 10-12, Gp 12-14)
//  14-22  Ao fp32
//  22-26  xb bf16 -> Qb overlays (xb dead after gemm_qkvg)
//  26-28  Wqb -> Kpk 26-27, Vpk 27-28 overlay
//  28-29.5 Wkb/Wvb/Wgb | 29.5-31.5 Wob | 31.5-32 cosT/sinT
// ---------------------------------------------------------------------------
extern "C" void kernel_launch(void* const* d_in, const int* in_sizes, int n_in,
                              void* d_out, int out_size, void* d_ws, size_t ws_size,
                              hipStream_t stream) {
    const float* x  = (const float*)d_in[0];
    const float* Wq = (const float*)d_in[1];
    const float* Wk = (const float*)d_in[2];
    const float* Wv = (const float*)d_in[3];
    const float* Wg = (const float*)d_in[4];
    const float* Wo = (const float*)d_in[5];
    const float* qg = (const float*)d_in[6];
    const float* lp = (const float*)d_in[7];
    float* out = (float*)d_out;

    char* ws = (char*)d_ws;
    float* Qp  = (float*)(ws);
    float* KVG = (float*)(ws + (8u  << 20));
    float* Kp  = KVG;
    float* Vp  = KVG + (size_t)S_LEN * KVDIM;
    float* Gp  = KVG + (size_t)2 * S_LEN * KVDIM;
    float* Ao  = (float*)(ws + (14u << 20));
    bf16* xb   = (bf16*)(ws + (22u << 20));
    bf16* Wqb  = (bf16*)(ws + (26u << 20));
    bf16* Wkb  = (bf16*)(ws + (28u << 20));
    bf16* Wvb  = (bf16*)(ws + (28u << 20) + (512u << 10));
    bf16* Wgb  = (bf16*)(ws + (29u << 20));
    bf16* Wob  = (bf16*)(ws + (29u << 20) + (512u << 10));
    float* cosT = (float*)(ws + (31u << 20) + (512u << 10));
    float* sinT = cosT + S_LEN * 32;
    bf16* Qb   = (bf16*)(ws + (22u << 20));  // overlays dead xb
    bf16* Kpk  = (bf16*)(ws + (26u << 20));  // overlays dead Wqb
    bf16* Vpk  = (bf16*)(ws + (27u << 20));
    bf16* Yb   = (bf16*)ws;                  // overlays dead Qp

    // 0. Casts + trig LUT (one dispatch)
    cast7<<<dim3(512, 7), 256, 0, stream>>>(x, Wq, Wk, Wv, Wg, Wo,
                                            xb, Wqb, Wkb, Wvb, Wgb, Wob,
                                            cosT, sinT);

    // 1. Fused Q/K/V/G projection (128x128 tiles, 224 blocks)
    gemm_qkvg<<<dim3(14, S_LEN/128), 256, 0, stream>>>(xb, Wqb, Wkb, Wvb, Wgb, Qp, KVG);

    // 2. Postproc: Q+K (LUT rotary, coalesced K repack), then V gate+pack
    postproc_qk<<<dim3(S_LEN, NH + NKVH), 64, 0, stream>>>(
        Qp, Kp, Qb, Kpk, qg, cosT, sinT);
    postproc_v<<<dim3(S_LEN/8, NKVH), 64, 0, stream>>>(Vp, Gp, Vpk);

    // 3. MFMA flash attention (verified R14)
    attn_mfma<<<4096, 64, 0, stream>>>(Qb, Kpk, Vpk, Ao);

    // 4. Lambda combine -> bf16 Y
    combine_kernel<<<S_LEN * DIM / 256, 256, 0, stream>>>(Ao, lp, Yb);

    // 5. Output projection (128x128 tiles, 128 blocks) -> fp32 out
    gemm_out<<<dim3(DIM/128, S_LEN/128), 256, 0, stream>>>(Yb, Wob, out);
}